// Round 4
// baseline (216.748 us; speedup 1.0000x reference)
//
#include <hip/hip_runtime.h>
#include <hip/hip_bf16.h>

#define NCLS 345
#define CPAD 384
#define DIM  512
#define BCAP 256

typedef float f32x4 __attribute__((ext_vector_type(4)));
typedef float f32x4u __attribute__((ext_vector_type(4), aligned(4)));
typedef short s16x8 __attribute__((ext_vector_type(8)));
typedef unsigned long long u64;

__device__ __forceinline__ short f2bf(float f) {
  union { float f; unsigned u; } v; v.f = f;
  unsigned r = v.u + 0x7fffu + ((v.u >> 16) & 1u);   // round-to-nearest-even
  return (short)(r >> 16);
}

__device__ __forceinline__ short f2bf_n(float f) {
  __hip_bfloat16 b = __float2bfloat16(f);             // RNE; compiler pairs to v_cvt_pk_bf16_f32
  union { __hip_bfloat16 b; short s; } u; u.b = b; return u.s;
}

// ---- Stage 1: one pass over N, bucket (ent_bits<<32)|idx per class ----
// ent in [0,1): positive-float bits are order-monotone, so u64 compare
// reproduces the stable (ent, idx) argsort order exactly.
__global__ __launch_bounds__(256) void scan_classes(
    const float* __restrict__ ent, const int* __restrict__ y_hat,
    u64* __restrict__ bucket, int* __restrict__ cnt, int N)
{
  int i = blockIdx.x * 256 + threadIdx.x;
  if (i >= N) return;
  int c = y_hat[i];
  unsigned eb = __float_as_uint(ent[i]);
  u64 key = ((u64)eb << 32) | (unsigned)i;
  int p = atomicAdd(&cnt[c], 1);
  if (p < BCAP) bucket[(size_t)c * BCAP + p] = key;
}

// ---- Stage 2: per-class select (exact stable rank) + normalized-row sum ----
__global__ __launch_bounds__(512) void select_accum(
    const float* __restrict__ supports, const u64* __restrict__ bucket,
    const int* __restrict__ cnt, const int* __restrict__ fKp,
    short* __restrict__ Wt)
{
  const int c = blockIdx.x;
  const int tid = threadIdx.x;
  const int lane = tid & 63, w = tid >> 6;
  __shared__ u64   s_key[BCAP];
  __shared__ int   s_selidx[BCAP];
  __shared__ int   s_nsel;
  __shared__ float s_part[8][DIM];   // 16 KB
  __shared__ float s_red[8];
  if (tid == 0) s_nsel = 0;
  const int S = (c < NCLS) ? min(cnt[c], BCAP) : 0;
  const int K = fKp[0];
  for (int e = tid; e < S; e += 512) s_key[e] = bucket[(size_t)c * BCAP + e];
  __syncthreads();
  for (int e = tid; e < S; e += 512) {
    u64 ke = s_key[e];
    int r = 0;
    for (int j = 0; j < S; ++j) r += (s_key[j] < ke) ? 1 : 0;
    if (r < K) { int p = atomicAdd(&s_nsel, 1); s_selidx[p] = (int)(unsigned)(ke & 0xffffffffull); }
  }
  __syncthreads();
  const int nsel = s_nsel;
  // 8 waves; 2 rows in flight per wave to overlap the shuffle chains
  f32x4 p0 = {0.f,0.f,0.f,0.f}, p1 = {0.f,0.f,0.f,0.f};
  for (int e0 = w; e0 < nsel; e0 += 16) {
    const int e1 = e0 + 8;
    const bool h1 = (e1 < nsel);                 // wave-uniform
    const f32x4* r0 = (const f32x4*)(supports + (size_t)s_selidx[e0] * DIM);
    f32x4 a0 = r0[lane], a1 = r0[lane + 64];
    f32x4 b0 = {0.f,0.f,0.f,0.f}, b1 = {0.f,0.f,0.f,0.f};
    if (h1) {
      const f32x4* r1 = (const f32x4*)(supports + (size_t)s_selidx[e1] * DIM);
      b0 = r1[lane]; b1 = r1[lane + 64];
    }
    float s0 = 0.f, s1 = 0.f;
#pragma unroll
    for (int j = 0; j < 4; ++j) {
      s0 = fmaf(a0[j], a0[j], s0); s0 = fmaf(a1[j], a1[j], s0);
      s1 = fmaf(b0[j], b0[j], s1); s1 = fmaf(b1[j], b1[j], s1);
    }
#pragma unroll
    for (int off = 32; off; off >>= 1) { s0 += __shfl_xor(s0, off); s1 += __shfl_xor(s1, off); }
    float c0 = 1.f / fmaxf(sqrtf(s0), 1e-12f);
    float c1 = 1.f / fmaxf(sqrtf(s1), 1e-12f);
#pragma unroll
    for (int j = 0; j < 4; ++j) { p0[j] = fmaf(a0[j], c0, p0[j]); p1[j] = fmaf(a1[j], c0, p1[j]); }
    if (h1) {
#pragma unroll
      for (int j = 0; j < 4; ++j) { p0[j] = fmaf(b0[j], c1, p0[j]); p1[j] = fmaf(b1[j], c1, p1[j]); }
    }
  }
  *(f32x4*)&s_part[w][lane * 4]       = p0;
  *(f32x4*)&s_part[w][256 + lane * 4] = p1;
  __syncthreads();
  float acc = 0.f;
#pragma unroll
  for (int ww = 0; ww < 8; ++ww) acc += s_part[ww][tid];
  float sq = acc * acc;
#pragma unroll
  for (int off = 32; off; off >>= 1) sq += __shfl_xor(sq, off);
  if (lane == 0) s_red[w] = sq;
  __syncthreads();
  float tot = 0.f;
#pragma unroll
  for (int ww = 0; ww < 8; ++ww) tot += s_red[ww];
  float sc = 1.f / fmaxf(sqrtf(tot), 1e-12f);
  Wt[(size_t)c * DIM + tid] = f2bf(acc * sc);
}

// ---- Kernel B: out[M,345] = z[M,512] @ W ----
// No LDS, no barriers: both MFMA operands loaded global->reg in fragment
// layout. A (z): 16 rows x 128B contiguous per fragment-pair (L3-resident).
// B (Wt, 384KB): L2-resident. 16 (kt,kk) steps, ping-pong reg buffers,
// prefetch distance 2 steps; waves fully independent -> latency hidden by
// TLP (no-LDS occupancy) + per-wave MLP.
__global__ __launch_bounds__(256) void gemm_zw(
    const float* __restrict__ z, const short* __restrict__ Wt,
    float* __restrict__ out)
{
  const int tid  = threadIdx.x;
  const int lane = tid & 63;
  const int wn   = tid >> 6;          // 0..3: N-quadrant
  const int bm   = blockIdx.x;        // rows bm*32 .. +31
  const int fr   = lane & 15, fq = lane >> 4;

  const float* a0 = z + (size_t)(bm * 32 + fr) * DIM + fq * 8;
  const float* a1 = a0 + (size_t)16 * DIM;
  const char* bb[6];
#pragma unroll
  for (int nt = 0; nt < 6; ++nt)
    bb[nt] = (const char*)Wt + (size_t)(wn * 96 + nt * 16 + fr) * (DIM * 2) + fq * 16;

  f32x4 acc[2][6];
#pragma unroll
  for (int mt = 0; mt < 2; ++mt)
#pragma unroll
    for (int nt = 0; nt < 6; ++nt) acc[mt][nt] = f32x4{0.f, 0.f, 0.f, 0.f};

  f32x4 Abuf[2][2][2];   // [parity][mt][half]
  s16x8 Bbuf[2][6];      // [parity][nt]

  // prologue: issue steps 0 and 1
#pragma unroll
  for (int s = 0; s < 2; ++s) {
    const int ka = s * 32;            // float offset  (kt*64 + kk*32)
#pragma unroll
    for (int nt = 0; nt < 6; ++nt)
      Bbuf[s][nt] = *(const s16x8*)(bb[nt] + s * 64);   // byte offset (kt*128 + kk*64)
    Abuf[s][0][0] = *(const f32x4*)(a0 + ka);
    Abuf[s][0][1] = *(const f32x4*)(a0 + ka + 4);
    Abuf[s][1][0] = *(const f32x4*)(a1 + ka);
    Abuf[s][1][1] = *(const f32x4*)(a1 + ka + 4);
  }

#pragma unroll
  for (int s = 0; s < 16; ++s) {
    const int p = s & 1;
    s16x8 a16[2];
#pragma unroll
    for (int mt = 0; mt < 2; ++mt)
#pragma unroll
      for (int j = 0; j < 4; ++j) {
        a16[mt][j]     = f2bf_n(Abuf[p][mt][0][j]);
        a16[mt][4 + j] = f2bf_n(Abuf[p][mt][1][j]);
      }
#pragma unroll
    for (int nt = 0; nt < 6; ++nt)
#pragma unroll
      for (int mt = 0; mt < 2; ++mt)
        acc[mt][nt] = __builtin_amdgcn_mfma_f32_16x16x32_bf16(Bbuf[p][nt], a16[mt], acc[mt][nt], 0, 0, 0);
    if (s + 2 < 16) {                 // prefetch into just-freed parity (WAR after MFMA issue)
      const int ka = (s + 2) * 32;
#pragma unroll
      for (int nt = 0; nt < 6; ++nt)
        Bbuf[p][nt] = *(const s16x8*)(bb[nt] + (s + 2) * 64);
      Abuf[p][0][0] = *(const f32x4*)(a0 + ka);
      Abuf[p][0][1] = *(const f32x4*)(a0 + ka + 4);
      Abuf[p][1][0] = *(const f32x4*)(a1 + ka);
      Abuf[p][1][1] = *(const f32x4*)(a1 + ka + 4);
    }
  }

  // epilogue (swapped-D layout): C-row = lane&15, C-col = fq*4 + reg j
  const int colb = wn * 96 + fq * 4;
#pragma unroll
  for (int mt = 0; mt < 2; ++mt) {
    const int row = bm * 32 + mt * 16 + fr;
    float* prow = out + (size_t)row * NCLS;
#pragma unroll
    for (int nt = 0; nt < 6; ++nt) {
      const int col = colb + nt * 16;
      if (col + 3 < NCLS) {
        *(f32x4u*)(prow + col) = acc[mt][nt];
      } else if (col < NCLS) {
#pragma unroll
        for (int j = 0; j < 4; ++j)
          if (col + j < NCLS) prow[col + j] = acc[mt][nt][j];
      }
    }
  }
}

extern "C" void kernel_launch(void* const* d_in, const int* in_sizes, int n_in,
                              void* d_out, int out_size, void* d_ws, size_t ws_size,
                              hipStream_t stream) {
  const float* z        = (const float*)d_in[0];
  const float* supports = (const float*)d_in[1];
  const float* ent      = (const float*)d_in[2];
  const int*   y_hat    = (const int*)d_in[3];
  const int*   fK       = (const int*)d_in[4];
  float* out = (float*)d_out;
  short* Wt  = (short*)d_ws;
  const int N = in_sizes[2];
  const int M = in_sizes[0] / DIM;

  const size_t offC = (size_t)CPAD * DIM * 2;          // 393216
  const size_t offB = offC + 2048;
  int* cnt    = (int*)((char*)d_ws + offC);
  u64* bucket = (u64*)((char*)d_ws + offB);
  hipMemsetAsync(cnt, 0, CPAD * sizeof(int), stream);
  scan_classes<<<dim3((N + 255) / 256), dim3(256), 0, stream>>>(ent, y_hat, bucket, cnt, N);
  select_accum<<<dim3(CPAD), dim3(512), 0, stream>>>(supports, bucket, cnt, fK, Wt);
  gemm_zw<<<dim3(M / 32), dim3(256), 0, stream>>>(z, Wt, out);
}

// Round 5
// 106.616 us; speedup vs baseline: 2.0330x; 2.0330x over previous
//
#include <hip/hip_runtime.h>
#include <hip/hip_bf16.h>

#define NCLS 345
#define CPAD 384
#define DIM  512
#define BCAP 256

typedef float f32x4 __attribute__((ext_vector_type(4)));
typedef float f32x4u __attribute__((ext_vector_type(4), aligned(4)));
typedef short s16x8 __attribute__((ext_vector_type(8)));
typedef unsigned long long u64;

__device__ __forceinline__ short f2bf(float f) {
  union { float f; unsigned u; } v; v.f = f;
  unsigned r = v.u + 0x7fffu + ((v.u >> 16) & 1u);   // round-to-nearest-even
  return (short)(r >> 16);
}

__device__ __forceinline__ short f2bf_n(float f) {
  __hip_bfloat16 b = __float2bfloat16(f);             // RNE; pairs to v_cvt_pk_bf16_f32
  union { __hip_bfloat16 b; short s; } u; u.b = b; return u.s;
}

// ---- Stage 1: one pass over N, bucket (ent_bits<<32)|idx per class ----
__global__ __launch_bounds__(256) void scan_classes(
    const float* __restrict__ ent, const int* __restrict__ y_hat,
    u64* __restrict__ bucket, int* __restrict__ cnt, int N)
{
  int i = blockIdx.x * 256 + threadIdx.x;
  if (i >= N) return;
  int c = y_hat[i];
  unsigned eb = __float_as_uint(ent[i]);
  u64 key = ((u64)eb << 32) | (unsigned)i;
  int p = atomicAdd(&cnt[c], 1);
  if (p < BCAP) bucket[(size_t)c * BCAP + p] = key;
}

// ---- Stage 2: per-class select (exact stable rank) + normalized-row sum ----
__global__ __launch_bounds__(512) void select_accum(
    const float* __restrict__ supports, const u64* __restrict__ bucket,
    const int* __restrict__ cnt, const int* __restrict__ fKp,
    short* __restrict__ Wt)
{
  const int c = blockIdx.x;
  const int tid = threadIdx.x;
  const int lane = tid & 63, w = tid >> 6;
  __shared__ u64   s_key[BCAP];
  __shared__ int   s_selidx[BCAP];
  __shared__ int   s_nsel;
  __shared__ float s_part[8][DIM];   // 16 KB
  __shared__ float s_red[8];
  if (tid == 0) s_nsel = 0;
  const int S = (c < NCLS) ? min(cnt[c], BCAP) : 0;
  const int K = fKp[0];
  for (int e = tid; e < S; e += 512) s_key[e] = bucket[(size_t)c * BCAP + e];
  __syncthreads();
  for (int e = tid; e < S; e += 512) {
    u64 ke = s_key[e];
    int r = 0;
    for (int j = 0; j < S; ++j) r += (s_key[j] < ke) ? 1 : 0;
    if (r < K) { int p = atomicAdd(&s_nsel, 1); s_selidx[p] = (int)(unsigned)(ke & 0xffffffffull); }
  }
  __syncthreads();
  const int nsel = s_nsel;
  f32x4 p0 = {0.f,0.f,0.f,0.f}, p1 = {0.f,0.f,0.f,0.f};
  for (int e0 = w; e0 < nsel; e0 += 16) {
    const int e1 = e0 + 8;
    const bool h1 = (e1 < nsel);
    const f32x4* r0 = (const f32x4*)(supports + (size_t)s_selidx[e0] * DIM);
    f32x4 a0 = r0[lane], a1 = r0[lane + 64];
    f32x4 b0 = {0.f,0.f,0.f,0.f}, b1 = {0.f,0.f,0.f,0.f};
    if (h1) {
      const f32x4* r1 = (const f32x4*)(supports + (size_t)s_selidx[e1] * DIM);
      b0 = r1[lane]; b1 = r1[lane + 64];
    }
    float s0 = 0.f, s1 = 0.f;
#pragma unroll
    for (int j = 0; j < 4; ++j) {
      s0 = fmaf(a0[j], a0[j], s0); s0 = fmaf(a1[j], a1[j], s0);
      s1 = fmaf(b0[j], b0[j], s1); s1 = fmaf(b1[j], b1[j], s1);
    }
#pragma unroll
    for (int off = 32; off; off >>= 1) { s0 += __shfl_xor(s0, off); s1 += __shfl_xor(s1, off); }
    float c0 = 1.f / fmaxf(sqrtf(s0), 1e-12f);
    float c1 = 1.f / fmaxf(sqrtf(s1), 1e-12f);
#pragma unroll
    for (int j = 0; j < 4; ++j) { p0[j] = fmaf(a0[j], c0, p0[j]); p1[j] = fmaf(a1[j], c0, p1[j]); }
    if (h1) {
#pragma unroll
      for (int j = 0; j < 4; ++j) { p0[j] = fmaf(b0[j], c1, p0[j]); p1[j] = fmaf(b1[j], c1, p1[j]); }
    }
  }
  *(f32x4*)&s_part[w][lane * 4]       = p0;
  *(f32x4*)&s_part[w][256 + lane * 4] = p1;
  __syncthreads();
  float acc = 0.f;
#pragma unroll
  for (int ww = 0; ww < 8; ++ww) acc += s_part[ww][tid];
  float sq = acc * acc;
#pragma unroll
  for (int off = 32; off; off >>= 1) sq += __shfl_xor(sq, off);
  if (lane == 0) s_red[w] = sq;
  __syncthreads();
  float tot = 0.f;
#pragma unroll
  for (int ww = 0; ww < 8; ++ww) tot += s_red[ww];
  float sc = 1.f / fmaxf(sqrtf(tot), 1e-12f);
  Wt[(size_t)c * DIM + tid] = f2bf(acc * sc);
}

// ---- Kernel B: out[M,345] = z[M,512] @ W ----
// Block-resident B panel: 192 cols x 256 K staged once per K-half in LDS
// (96 KB, XOR-swizzled). 8 waves x 32 rows free-run with no per-K barriers;
// A loaded global->reg (L3-resident), distance-1 prefetch. 3 barriers total.
__global__ __launch_bounds__(512, 2) void gemm_zw(
    const float* __restrict__ z, const short* __restrict__ Wt,
    float* __restrict__ out)
{
  __shared__ __align__(16) char lB[192 * 512];   // 96 KB: [192 rows][256 K x 2B]
  const int tid  = threadIdx.x;
  const int lane = tid & 63;
  const int w    = tid >> 6;               // wave 0..7
  const int p    = blockIdx.x >> 8;        // N-panel 0..1 (192 cols each)
  const int mch  = blockIdx.x & 255;       // M-chunk (256 rows)
  const int fr   = lane & 15, fq = lane >> 4;
  const int Mbase = mch * 256;

  // staging addresses: q = i*512 + tid; row = q/32, 16B chunk q%32
  const char* gstage = (const char*)(Wt + (size_t)p * 192 * DIM);

  // per-wave A pointers: rows Mbase + w*32 + mt*16 + fr
  const float* a0 = z + (size_t)(Mbase + w * 32 + fr) * DIM + fq * 8;
  const float* a1 = a0 + (size_t)16 * DIM;

  // B-fragment LDS byte offsets (nt, ks): row = nt*16+fr
  unsigned roB[12];
#pragma unroll
  for (int nt = 0; nt < 12; ++nt) {
    int r = nt * 16 + fr;
    roB[nt] = (unsigned)(r * 512) + (((unsigned)(fq * 16)) ^ (((unsigned)(r & 7)) << 4));
  }

  f32x4 acc[2][12];
#pragma unroll
  for (int mt = 0; mt < 2; ++mt)
#pragma unroll
    for (int nt = 0; nt < 12; ++nt) acc[mt][nt] = f32x4{0.f, 0.f, 0.f, 0.f};

#pragma unroll
  for (int h = 0; h < 2; ++h) {
    // ---- stage K-half h: 96 KB, coalesced read, swizzled LDS write ----
    if (h) __syncthreads();                 // all waves done reading half 0
#pragma unroll
    for (int i = 0; i < 12; ++i) {
      int q = i * 512 + tid;
      int row = q >> 5, c16 = (q & 31) << 4;
      s16x8 v = *(const s16x8*)(gstage + (size_t)row * 1024 + h * 512 + c16);
      *(s16x8*)(lB + row * 512 + (c16 ^ ((row & 7) << 4))) = v;
    }
    __syncthreads();

    // ---- compute: 8 K-steps of 32, no barriers ----
    f32x4 Ac[2][2], An[2][2];
    const int kb = h * 256;                 // float offset of this K-half
    Ac[0][0] = *(const f32x4*)(a0 + kb);     Ac[0][1] = *(const f32x4*)(a0 + kb + 4);
    Ac[1][0] = *(const f32x4*)(a1 + kb);     Ac[1][1] = *(const f32x4*)(a1 + kb + 4);
#pragma unroll
    for (int ks = 0; ks < 8; ++ks) {
      if (ks < 7) {                          // distance-1 A prefetch
        const int ka = kb + (ks + 1) * 32;
        An[0][0] = *(const f32x4*)(a0 + ka); An[0][1] = *(const f32x4*)(a0 + ka + 4);
        An[1][0] = *(const f32x4*)(a1 + ka); An[1][1] = *(const f32x4*)(a1 + ka + 4);
      }
      s16x8 a16[2];
#pragma unroll
      for (int mt = 0; mt < 2; ++mt)
#pragma unroll
        for (int j = 0; j < 4; ++j) {
          a16[mt][j]     = f2bf_n(Ac[mt][0][j]);
          a16[mt][4 + j] = f2bf_n(Ac[mt][1][j]);
        }
      const unsigned kx = (unsigned)(ks * 64);
#pragma unroll
      for (int g = 0; g < 2; ++g) {          // 2 groups of 6 nt: limit live B-frags
        s16x8 bfr[6];
#pragma unroll
        for (int t = 0; t < 6; ++t)
          bfr[t] = *(const s16x8*)(lB + (roB[g * 6 + t] ^ kx));
#pragma unroll
        for (int t = 0; t < 6; ++t)
#pragma unroll
          for (int mt = 0; mt < 2; ++mt)
            acc[mt][g * 6 + t] = __builtin_amdgcn_mfma_f32_16x16x32_bf16(
                bfr[t], a16[mt], acc[mt][g * 6 + t], 0, 0, 0);
      }
      Ac[0][0] = An[0][0]; Ac[0][1] = An[0][1];
      Ac[1][0] = An[1][0]; Ac[1][1] = An[1][1];
    }
  }

  // epilogue (swapped-D): C-row = fr (z row), C-col = fq*4 + reg j
  const int colp = p * 192 + fq * 4;
#pragma unroll
  for (int mt = 0; mt < 2; ++mt) {
    const int row = Mbase + w * 32 + mt * 16 + fr;
    float* prow = out + (size_t)row * NCLS;
#pragma unroll
    for (int nt = 0; nt < 12; ++nt) {
      const int col = colp + nt * 16;
      if (col + 3 < NCLS) {
        *(f32x4u*)(prow + col) = acc[mt][nt];
      } else if (col < NCLS) {
#pragma unroll
        for (int j = 0; j < 4; ++j)
          if (col + j < NCLS) prow[col + j] = acc[mt][nt][j];
      }
    }
  }
}

extern "C" void kernel_launch(void* const* d_in, const int* in_sizes, int n_in,
                              void* d_out, int out_size, void* d_ws, size_t ws_size,
                              hipStream_t stream) {
  const float* z        = (const float*)d_in[0];
  const float* supports = (const float*)d_in[1];
  const float* ent      = (const float*)d_in[2];
  const int*   y_hat    = (const int*)d_in[3];
  const int*   fK       = (const int*)d_in[4];
  float* out = (float*)d_out;
  short* Wt  = (short*)d_ws;
  const int N = in_sizes[2];
  const int M = in_sizes[0] / DIM;

  const size_t offC = (size_t)CPAD * DIM * 2;          // 393216
  const size_t offB = offC + 2048;
  int* cnt    = (int*)((char*)d_ws + offC);
  u64* bucket = (u64*)((char*)d_ws + offB);
  hipMemsetAsync(cnt, 0, CPAD * sizeof(int), stream);
  scan_classes<<<dim3((N + 255) / 256), dim3(256), 0, stream>>>(ent, y_hat, bucket, cnt, N);
  select_accum<<<dim3(CPAD), dim3(512), 0, stream>>>(supports, bucket, cnt, fK, Wt);
  gemm_zw<<<dim3(2 * (M / 256)), dim3(512), 0, stream>>>(z, Wt, out);
}